// Round 4
// baseline (716.979 us; speedup 1.0000x reference)
//
#include <hip/hip_runtime.h>
#include <stdint.h>

#define BATCH 64
#define NPTS 16384
#define MODEL_DIM 512
#define QL 2048
#define NROWS (BATCH * QL)

typedef unsigned short u16;
typedef __attribute__((ext_vector_type(8))) __bf16 bf16x8;
typedef __attribute__((ext_vector_type(4))) float f32x4;

// flags: [0..5] bf16? for boxes,scores,w1,b1,w2,b2; [6] labels-int64?; [7] valid-bool?
// out dtype = flags[0] (reference: outputs carry object_boxes.dtype)

__device__ __forceinline__ float loadf(const void* p, size_t i, uint32_t bf) {
  if (bf) {
    uint32_t u = ((const u16*)p)[i];
    return __uint_as_float(u << 16);
  }
  return ((const float*)p)[i];
}

__device__ __forceinline__ u16 f2bf_bits(float f) {
  __bf16 h = (__bf16)f;  // RNE
  return *(const u16*)&h;
}

__device__ __forceinline__ void storef(void* p, size_t i, float v, uint32_t bf) {
  if (bf) ((u16*)p)[i] = f2bf_bits(v);
  else ((float*)p)[i] = v;
}

__device__ __forceinline__ int load_label(const void* p, size_t i, uint32_t is64) {
  return is64 ? ((const int*)p)[2 * i] : ((const int*)p)[i];  // LE low word
}

__device__ __forceinline__ int load_valid(const void* p, size_t i, uint32_t isbool) {
  return isbool ? (int)((const unsigned char*)p)[i] : ((const int*)p)[i];
}

// ---------------------------------------------------------------------------
// Kernel 0: runtime dtype sniffer -> fl[8] in d_ws.
// ---------------------------------------------------------------------------
__global__ void sniff_kernel(const void* boxes, const void* scores,
                             const void* w1, const void* b1, const void* w2,
                             const void* b2, const void* labels,
                             const void* valid, uint32_t* fl) {
  if (threadIdx.x != 0 || blockIdx.x != 0) return;
  const void* bufs[6] = {boxes, scores, w1, b1, w2, b2};
  for (int t = 0; t < 6; ++t) {
    const u16* w = (const u16*)bufs[t];
    int c = 0, z = 0;
    for (int i = 0; i < 64; ++i) {
      u16 v = w[i];
      if (v == 0) ++z;
      uint32_t e = (v >> 7) & 0xFFu;
      if (e >= 100u && e <= 135u) ++c;
    }
    // all-zero buffer (b1/b2): read as bf16 — values are 0 either way and it
    // never reads past the smaller possible buffer size.
    fl[t] = (z >= 60) ? 1u : (c >= 56 ? 1u : 0u);
  }
  const uint32_t* lw = (const uint32_t*)labels;
  uint32_t odnz = 0;
  for (int i = 0; i < 32; ++i) odnz |= lw[2 * i + 1];
  fl[6] = (odnz == 0u) ? 1u : 0u;  // int64 iff high words all zero
  const uint32_t* vw = (const uint32_t*)valid;
  uint32_t anybig = 0;
  for (int i = 0; i < 64; ++i) anybig |= (vw[i] > 1u) ? 1u : 0u;
  fl[7] = anybig;  // bool-packed iff any word has non-{0,1} value
}

// ---------------------------------------------------------------------------
// Kernel 1: w2 [K][N] (generic dtype) -> w2t [N][K] bf16 bits in d_ws.
// ---------------------------------------------------------------------------
__global__ void w2_transpose_kernel(const void* __restrict__ w2,
                                    u16* __restrict__ w2t,
                                    const uint32_t* __restrict__ fl) {
  __shared__ u16 tile[32][33];
  const uint32_t bf = fl[4];
  const int bx = blockIdx.x, by = blockIdx.y;
  const int tx = threadIdx.x, ty = threadIdx.y;
#pragma unroll
  for (int p = 0; p < 4; ++p) {
    int k = bx * 32 + ty + p * 8;
    int n = by * 32 + tx;
    tile[ty + p * 8][tx] = f2bf_bits(loadf(w2, (size_t)k * MODEL_DIM + n, bf));
  }
  __syncthreads();
#pragma unroll
  for (int p = 0; p < 4; ++p) {
    int n = by * 32 + ty + p * 8;
    int k = bx * 32 + tx;
    w2t[(size_t)n * MODEL_DIM + k] = tile[tx][ty + p * 8];
  }
}

// ---------------------------------------------------------------------------
// Kernel 2: per-batch top-2048. 64-bit key = orderable(float score) << 32 |
// ~idx — distinct keys, jax stable tie-break. 8-pass radix select + bitonic.
// ---------------------------------------------------------------------------
__global__ __launch_bounds__(1024) void topk_kernel(
    const void* __restrict__ scores, const void* __restrict__ valid,
    u16* __restrict__ idxbuf, const uint32_t* __restrict__ fl) {
  __shared__ uint32_t sk[NPTS];       // 64 KB (score orderable)
  __shared__ uint64_t sel[QL];        // 16 KB
  __shared__ uint32_t hist[256];
  __shared__ uint32_t s_cnt, s_r;
  __shared__ uint64_t s_prefix;

  const uint32_t sbf = fl[1], vbool = fl[7];
  const int b = blockIdx.x;
  const int tid = threadIdx.x;

  for (int i = tid; i < NPTS; i += 1024) {
    size_t g = (size_t)b * NPTS + i;
    float ms = load_valid(valid, g, vbool) ? loadf(scores, g, sbf) : -1e30f;
    uint32_t u = __float_as_uint(ms);
    sk[i] = (u & 0x80000000u) ? ~u : (u | 0x80000000u);
  }
  if (tid == 0) { s_prefix = 0ull; s_r = QL; s_cnt = 0u; }
  __syncthreads();

  for (int bp = 7; bp >= 0; --bp) {
    if (tid < 256) hist[tid] = 0u;
    __syncthreads();
    const uint64_t prefix = s_prefix;
    const int shift = 8 * bp;
    for (int i = tid; i < NPTS; i += 1024) {
      uint64_t k = ((uint64_t)sk[i] << 32) | (uint32_t)(~i);
      bool match = (bp == 7) || ((k >> (shift + 8)) == prefix);
      if (match) atomicAdd(&hist[(uint32_t)(k >> shift) & 0xFFu], 1u);
    }
    __syncthreads();
    if (tid == 0) {
      uint32_t r = s_r, cum = 0u, chosen = 0u;
      for (int v = 255; v >= 0; --v) {
        uint32_t h = hist[v];
        if (cum + h >= r) { chosen = (uint32_t)v; r -= cum; break; }
        cum += h;
      }
      s_prefix = (prefix << 8) | chosen;
      s_r = r;
      s_cnt = 0u;
    }
    __syncthreads();
  }
  const uint64_t V = s_prefix;

  for (int i = tid; i < QL; i += 1024) sel[i] = 0ull;
  __syncthreads();

  for (int i = tid; i < NPTS; i += 1024) {
    uint64_t k = ((uint64_t)sk[i] << 32) | (uint32_t)(~i);
    if (k >= V) {
      uint32_t p = atomicAdd(&s_cnt, 1u);
      if (p < QL) sel[p] = k;
    }
  }
  __syncthreads();

  for (int kk = 2; kk <= QL; kk <<= 1) {
    for (int j = kk >> 1; j > 0; j >>= 1) {
      for (int i = tid; i < QL; i += 1024) {
        int l = i ^ j;
        if (l > i) {
          uint64_t a = sel[i], c = sel[l];
          bool dir = ((i & kk) == 0);
          if ((a < c) == dir) { sel[i] = c; sel[l] = a; }
        }
      }
      __syncthreads();
    }
  }

  for (int q = tid; q < QL; q += 1024)
    idxbuf[b * QL + q] = (u16)((~(uint32_t)sel[q]) & (NPTS - 1));
}

// ---------------------------------------------------------------------------
// Kernel 3: fused MLP, 128 rows/block. Generic-dtype gathers; fp32 GEMM1
// (one-hot = w1 row lookup) + relu -> LDS bf16; bf16 MFMA GEMM2; store out.
// ---------------------------------------------------------------------------
__global__ __launch_bounds__(256) void mlp_kernel(
    const void* __restrict__ w1, const void* __restrict__ b1,
    const u16* __restrict__ w2t, const void* __restrict__ b2,
    const u16* __restrict__ idxbuf, const void* __restrict__ boxes,
    const void* __restrict__ scores, const void* __restrict__ labels,
    const void* __restrict__ valid, void* __restrict__ out,
    const uint32_t* __restrict__ fl) {
  __shared__ float4 rowf4[384];     // rowdata[128][12]
  __shared__ bf16x8 hid8[128][65];  // hid[128][520] bf16
  float* rowdata = (float*)rowf4;
  __bf16* hid = (__bf16*)hid8;
  const __bf16* w2tb = (const __bf16*)w2t;

  const uint32_t bxbf = fl[0], scbf = fl[1], w1bf = fl[2], b1bf = fl[3];
  const uint32_t b2bf = fl[5], l64 = fl[6], vbool = fl[7];
  const uint32_t outbf = fl[0];

  const int tid = threadIdx.x;
  const size_t row0 = (size_t)blockIdx.x * 128;
  const int b = (int)(row0 >> 11);

  for (int r = tid; r < 128; r += 256) {
    int idx = idxbuf[row0 + r] & (NPTS - 1);
    size_t src = (size_t)b * NPTS + idx;
    float* rr = rowdata + r * 12;
#pragma unroll
    for (int f = 0; f < 9; ++f) rr[f] = loadf(boxes, src * 9 + f, bxbf);
    rr[9] = loadf(scores, src, scbf);
    int lab = load_label(labels, src, l64);
    lab = lab < 0 ? 0 : (lab > 22 ? 22 : lab);
    rr[10] = (float)lab;
    rr[11] = load_valid(valid, src, vbool) ? 1.0f : 0.0f;
  }

  float w1c0[10], w1c1[10];
#pragma unroll
  for (int f = 0; f < 10; ++f) {
    w1c0[f] = loadf(w1, f * MODEL_DIM + tid, w1bf);
    w1c1[f] = loadf(w1, f * MODEL_DIM + tid + 256, w1bf);
  }
  const float b1a = loadf(b1, tid, b1bf), b1b = loadf(b1, tid + 256, b1bf);
  __syncthreads();

#pragma unroll 2
  for (int r = 0; r < 128; ++r) {
    int lab = (int)rowdata[r * 12 + 10];
    size_t ohbase = (size_t)(10 + lab) * MODEL_DIM;
    float h0 = b1a + loadf(w1, ohbase + tid, w1bf);
    float h1 = b1b + loadf(w1, ohbase + tid + 256, w1bf);
#pragma unroll
    for (int f = 0; f < 10; ++f) {
      float ft = rowdata[r * 12 + f];
      h0 = fmaf(ft, w1c0[f], h0);
      h1 = fmaf(ft, w1c1[f], h1);
    }
    hid[r * 520 + tid] = (__bf16)fmaxf(h0, 0.0f);
    hid[r * 520 + tid + 256] = (__bf16)fmaxf(h1, 0.0f);
  }
  __syncthreads();

  const int wave = tid >> 6;
  const int lane = tid & 63;
  const int quad = lane >> 4;
  const int l16 = lane & 15;

  for (int ng = 0; ng < 4; ++ng) {
    f32x4 acc[8][2];
#pragma unroll
    for (int mt = 0; mt < 8; ++mt)
#pragma unroll
      for (int nt = 0; nt < 2; ++nt)
        acc[mt][nt] = f32x4{0.0f, 0.0f, 0.0f, 0.0f};

    const int nbase = wave * 128 + ng * 32;
    for (int ks = 0; ks < 16; ++ks) {
      bf16x8 a[8];
#pragma unroll
      for (int mt = 0; mt < 8; ++mt)
        a[mt] = hid8[mt * 16 + l16][ks * 4 + quad];
      bf16x8 bb[2];
#pragma unroll
      for (int nt = 0; nt < 2; ++nt) {
        int n = nbase + nt * 16 + l16;
        bb[nt] = *(const bf16x8*)&w2tb[(size_t)n * MODEL_DIM + ks * 32 + quad * 8];
      }
#pragma unroll
      for (int mt = 0; mt < 8; ++mt)
#pragma unroll
        for (int nt = 0; nt < 2; ++nt)
          acc[mt][nt] = __builtin_amdgcn_mfma_f32_16x16x32_bf16(
              a[mt], bb[nt], acc[mt][nt], 0, 0, 0);
    }

    // C/D layout: col = lane&15 (n), row = quad*4+reg (m)
#pragma unroll
    for (int mt = 0; mt < 8; ++mt) {
#pragma unroll
      for (int nt = 0; nt < 2; ++nt) {
        int n = nbase + nt * 16 + l16;
        float bias = loadf(b2, n, b2bf);
#pragma unroll
        for (int reg = 0; reg < 4; ++reg) {
          int m = mt * 16 + quad * 4 + reg;
          float vmask = rowdata[m * 12 + 11];
          float val = acc[mt][nt][reg] + bias;
          storef(out, (row0 + m) * MODEL_DIM + n,
                 (vmask != 0.0f) ? val : 0.0f, outbf);
        }
      }
    }
  }
}

// ---------------------------------------------------------------------------
// Kernel 4: write refs / scores outputs (offsets in elements of out dtype).
// ---------------------------------------------------------------------------
__global__ __launch_bounds__(256) void finalize_kernel(
    const u16* __restrict__ idxbuf, const void* __restrict__ boxes,
    const void* __restrict__ scores, const void* __restrict__ valid,
    void* __restrict__ out, const uint32_t* __restrict__ fl) {
  const uint32_t bxbf = fl[0], scbf = fl[1], vbool = fl[7], outbf = fl[0];
  int r = blockIdx.x * 256 + threadIdx.x;
  if (r >= NROWS) return;
  int idx = idxbuf[r] & (NPTS - 1);
  int b = r >> 11;
  size_t src = (size_t)b * NPTS + idx;
  int v = load_valid(valid, src, vbool);
  float s = v ? loadf(scores, src, scbf) : 0.0f;
  float x = v ? loadf(boxes, src * 9 + 0, bxbf) : 0.0f;
  float y = v ? loadf(boxes, src * 9 + 1, bxbf) : 0.0f;
  float z = v ? loadf(boxes, src * 9 + 2, bxbf) : 0.0f;
  const size_t refs0 = (size_t)NROWS * MODEL_DIM;
  const size_t scr0 = refs0 + (size_t)NROWS * 3;
  storef(out, refs0 + (size_t)r * 3 + 0, x, outbf);
  storef(out, refs0 + (size_t)r * 3 + 1, y, outbf);
  storef(out, refs0 + (size_t)r * 3 + 2, z, outbf);
  storef(out, scr0 + r, s, outbf);
}

extern "C" void kernel_launch(void* const* d_in, const int* in_sizes, int n_in,
                              void* d_out, int out_size, void* d_ws, size_t ws_size,
                              hipStream_t stream) {
  const void* boxes  = d_in[0];
  const void* scores = d_in[1];
  const void* w1     = d_in[2];
  const void* b1     = d_in[3];
  const void* w2     = d_in[4];
  const void* b2     = d_in[5];
  const void* labels = d_in[6];
  const void* valid  = d_in[7];

  // d_ws layout: flags[16] u32 @0; w2t u16[512*512] @256; idxbuf u16 @256+512K
  uint32_t* fl = (uint32_t*)d_ws;
  u16* w2t    = (u16*)((char*)d_ws + 256);
  u16* idxbuf = (u16*)((char*)d_ws + 256 + (size_t)MODEL_DIM * MODEL_DIM * 2);

  sniff_kernel<<<1, 64, 0, stream>>>(boxes, scores, w1, b1, w2, b2, labels,
                                     valid, fl);
  w2_transpose_kernel<<<dim3(16, 16), dim3(32, 8), 0, stream>>>(w2, w2t, fl);
  topk_kernel<<<BATCH, 1024, 0, stream>>>(scores, valid, idxbuf, fl);
  mlp_kernel<<<NROWS / 128, 256, 0, stream>>>(w1, b1, w2t, b2, idxbuf, boxes,
                                              scores, labels, valid, d_out, fl);
  finalize_kernel<<<(NROWS + 255) / 256, 256, 0, stream>>>(idxbuf, boxes,
                                                           scores, valid,
                                                           d_out, fl);
}